// Round 4
// baseline (224.706 us; speedup 1.0000x reference)
//
#include <hip/hip_runtime.h>
#include <stdint.h>
#include <stddef.h>

#define IN_F   1024
#define OUT_F  1024
#define NROWS  16384
#define NTERMS 10

typedef __bf16 bf16x8 __attribute__((ext_vector_type(8)));
typedef float  f32x16 __attribute__((ext_vector_type(16)));
typedef unsigned short u16x8 __attribute__((ext_vector_type(8)));

union V8 { u16x8 u; bf16x8 b; };

__device__ __forceinline__ unsigned short f2bf(float f) {
    unsigned int u = __float_as_uint(f);
    unsigned int r = (u + 0x7FFFu + ((u >> 16) & 1u)) >> 16;
    return (unsigned short)r;
}

// ---------------------------------------------------------------- cast x -> bf16
__global__ void cast_x_kernel(const float* __restrict__ x, unsigned short* __restrict__ xb) {
    size_t i = ((size_t)blockIdx.x * 256 + threadIdx.x) * 8;
    float4 a = *(const float4*)(x + i);
    float4 b = *(const float4*)(x + i + 4);
    u16x8 o;
    o[0] = f2bf(a.x); o[1] = f2bf(a.y); o[2] = f2bf(a.z); o[3] = f2bf(a.w);
    o[4] = f2bf(b.x); o[5] = f2bf(b.y); o[6] = f2bf(b.z); o[7] = f2bf(b.w);
    *(u16x8*)(xb + i) = o;
}

// ------------------------------------------- base W -> bf16 ; mean spline W -> bf16
__global__ __launch_bounds__(256)
void prep_w_kernel(const float* __restrict__ bw, const float* __restrict__ sw,
                   unsigned short* __restrict__ wb, unsigned short* __restrict__ wm) {
    __shared__ float s[256 * NTERMS];
    const int tid = threadIdx.x;
    const size_t base = (size_t)blockIdx.x * 256;
    const float4* src = (const float4*)(sw + base * NTERMS);
#pragma unroll
    for (int it = 0; it < 3; ++it) {
        int j = tid + it * 256;
        if (j < (256 * NTERMS) / 4) ((float4*)s)[j] = src[j];
    }
    __syncthreads();
    float sum = 0.f;
#pragma unroll
    for (int t = 0; t < NTERMS; ++t) sum += s[tid * NTERMS + t];
    size_t i = base + tid;
    wm[i] = f2bf(sum * 0.1f);
    wb[i] = f2bf(bw[i]);
}

// ---------------------------------------------------------------- fused dual GEMM
// out[m][n] = silu( sum_k x[m][k]*Wb[n][k] ) + sum_k x[m][k]*Wm[n][k]
//
// ROUND-4: revert to the round-0 2-barrier structure (proven best: 70 µs),
// swap MFMA shape 16x16x32 -> 32x32x16 (ceiling 2075 -> 2495 TF, half the
// MFMA instruction count). 128x128 tile, 256 thr = 4 waves (2M x 2N), each
// wave owns 64x64 x {base,spline} as 2x2 tiles of 32x32. BK=64.
//
// Swizzle: 32x32 frag reads span 32 consecutive rows at a FIXED k-chunk, so
// the old  c ^ (r&7)  would 4-way alias (rows r,r+8,r+16,r+24 same bank set).
// New per-row chunk permutation:  c ^ (r&7) ^ (((r>>3)&3)<<1)  — XOR bijection
// per row; any 16 consecutive rows cover all 8 slots exactly twice (2-way =
// free, m136). Staging pre-permutes the global source with the same mask
// (both-sides rule); mask is invariant across the staging j-loop (row steps
// of 32 ≡ 0 mod 8 and row-group steps ≡ 0 mod 4), so sgc is one constant.
#define GLL16(GP, LP) __builtin_amdgcn_global_load_lds( \
    (const __attribute__((address_space(1))) unsigned int*)(GP), \
    (__attribute__((address_space(3))) unsigned int*)(LP), 16, 0, 0)

__global__ __launch_bounds__(256, 2)
void kan_gemm(const unsigned short* __restrict__ xb,
              const unsigned short* __restrict__ wbq,
              const unsigned short* __restrict__ wmq,
              float* __restrict__ out)
{
    __shared__ __align__(16) unsigned short As[128 * 64];
    __shared__ __align__(16) unsigned short Bs[2][128 * 64];

    const int tid  = threadIdx.x;
    const int lane = tid & 63;
    const int wave = tid >> 6;
    const int wm_  = wave >> 1;      // M half
    const int wn_  = wave & 1;       // N half
    const int rowx = lane & 31;      // row within a 32-tile
    const int hi   = lane >> 5;      // k-half (8 elements each)

    const int m0 = blockIdx.x * 128;
    const int n0 = blockIdx.y * 128;

    f32x16 acc[2][2][2];             // [s][mt][nt]
#pragma unroll
    for (int s = 0; s < 2; ++s)
#pragma unroll
        for (int mt = 0; mt < 2; ++mt)
#pragma unroll
            for (int nt = 0; nt < 2; ++nt)
                acc[s][mt][nt] = (f32x16){0.f,0.f,0.f,0.f,0.f,0.f,0.f,0.f,
                                          0.f,0.f,0.f,0.f,0.f,0.f,0.f,0.f};

    // staging: 1024 chunks (16 B) per 128x64 tile, 4 per thread per tile.
    // q = tid + j*256 -> row r = q>>3, dest slot cd = q&7. Global chunk =
    // cd ^ msk(r); msk(r) = (r&7) ^ (((r>>3)&3)<<1) is j-invariant:
    const int r0  = tid >> 3;
    const int sgc = (tid & 7) ^ (r0 & 7) ^ (((r0 >> 3) & 3) << 1);

    for (int k0 = 0; k0 < IN_F; k0 += 64) {
        __syncthreads();
#pragma unroll
        for (int j = 0; j < 4; ++j) {
            int q = tid + j * 256;
            int r = r0 + j * 32;
            const unsigned short* ga = xb + (size_t)(m0 + r) * IN_F + k0 + sgc * 8;
            GLL16(ga, As + q * 8);
            const unsigned short* gb = wbq + (size_t)(n0 + r) * IN_F + k0 + sgc * 8;
            GLL16(gb, Bs[0] + q * 8);
            const unsigned short* gm = wmq + (size_t)(n0 + r) * IN_F + k0 + sgc * 8;
            GLL16(gm, Bs[1] + q * 8);
        }
        __syncthreads();

#pragma unroll
        for (int ks = 0; ks < 4; ++ks) {
            bf16x8 af[2], bf[2][2];
            const int X = ks * 2 + hi;   // logical k-chunk for this frag
#pragma unroll
            for (int mt = 0; mt < 2; ++mt) {
                int r = (wm_ * 64) + mt * 32 + rowx;
                int slot = X ^ (r & 7) ^ (((r >> 3) & 3) << 1);
                union V8 t;
                t.u = *(const u16x8*)(As + r * 64 + slot * 8);
                af[mt] = t.b;
            }
#pragma unroll
            for (int s = 0; s < 2; ++s)
#pragma unroll
                for (int nt = 0; nt < 2; ++nt) {
                    int r = (wn_ * 64) + nt * 32 + rowx;
                    int slot = X ^ (r & 7) ^ (((r >> 3) & 3) << 1);
                    union V8 t;
                    t.u = *(const u16x8*)(Bs[s] + r * 64 + slot * 8);
                    bf[s][nt] = t.b;
                }
#pragma unroll
            for (int s = 0; s < 2; ++s)
#pragma unroll
                for (int mt = 0; mt < 2; ++mt)
#pragma unroll
                    for (int nt = 0; nt < 2; ++nt)
                        acc[s][mt][nt] = __builtin_amdgcn_mfma_f32_32x32x16_bf16(
                            af[mt], bf[s][nt], acc[s][mt][nt], 0, 0, 0);
        }
    }

    // epilogue: silu(base) + spline, fp32 store
    // C/D layout (32x32): col = lane&31, row = (reg&3) + 8*(reg>>2) + 4*(lane>>5)
#pragma unroll
    for (int mt = 0; mt < 2; ++mt)
#pragma unroll
        for (int nt = 0; nt < 2; ++nt)
#pragma unroll
            for (int r = 0; r < 16; ++r) {
                float vb = acc[0][mt][nt][r];
                float vm = acc[1][mt][nt][r];
                float o  = vb / (1.0f + __expf(-vb)) + vm;
                int row = m0 + wm_ * 64 + mt * 32 + (r & 3) + 8 * (r >> 2) + 4 * hi;
                int col = n0 + wn_ * 64 + nt * 32 + rowx;
                out[(size_t)row * OUT_F + col] = o;
            }
}

extern "C" void kernel_launch(void* const* d_in, const int* in_sizes, int n_in,
                              void* d_out, int out_size, void* d_ws, size_t ws_size,
                              hipStream_t stream) {
    const float* x  = (const float*)d_in[0];   // [16384,1024]
    const float* bw = (const float*)d_in[1];   // [1024,1024]
    const float* sw = (const float*)d_in[2];   // [1024,1024,10]
    float* out = (float*)d_out;                // [16384,1024]

    unsigned short* xb  = (unsigned short*)d_ws;
    unsigned short* wbq = xb + (size_t)NROWS * IN_F;
    unsigned short* wmq = wbq + (size_t)OUT_F * IN_F;

    cast_x_kernel<<<dim3((NROWS * IN_F) / (256 * 8)), dim3(256), 0, stream>>>(x, xb);
    prep_w_kernel<<<dim3((OUT_F * IN_F) / 256), dim3(256), 0, stream>>>(bw, sw, wbq, wmq);
    kan_gemm<<<dim3(NROWS / 128, OUT_F / 128), dim3(256), 0, stream>>>(xb, wbq, wmq, out);
}